// Round 15
// baseline (154.892 us; speedup 1.0000x reference)
//
#include <hip/hip_runtime.h>
#include <math.h>

#define BQ 4
#define LQ 4104
#define NTQ 4096
#define CDIM 320
#define DIP 1352
#define DI 640
#define CONVD 704
#define NH 8
#define HD 80
#define DS 32
#define MQ (BQ*LQ)   // 16416
#define QC 64        // chunk length
#define NC 65        // ceil(LQ/QC)

typedef __attribute__((ext_vector_type(8))) short bf16x8;
typedef __attribute__((ext_vector_type(4))) float f32x4;

__device__ __forceinline__ unsigned short f2bf(float f){
  union { float f; unsigned u; } v; v.f = f;
  unsigned r = v.u + 0x7FFFu + ((v.u >> 16) & 1u);
  return (unsigned short)(r >> 16);
}
__device__ __forceinline__ float bf2f(unsigned short u){
  union { unsigned u; float f; } v; v.u = ((unsigned)u) << 16;
  return v.f;
}
__device__ __forceinline__ float warp_sum(float v){
  #pragma unroll
  for (int o = 32; o; o >>= 1) v += __shfl_xor(v, o);
  return v;
}
__device__ __forceinline__ void gload16(const unsigned short* g, unsigned short* l){
  __builtin_amdgcn_global_load_lds(
      (const __attribute__((address_space(1))) unsigned int*)g,
      (__attribute__((address_space(3))) unsigned int*)l, 16, 0, 0);
}
__device__ __forceinline__ int swz64(int p, int i){
  return p*QC + (i ^ ((p & 7) << 3));
}

// ---------------- K0: prologue: weight converts (rsw folded into w2) + point-token LN ----------------
__global__ __launch_bounds__(256) void k_prep(
    const float* __restrict__ w1, unsigned short* __restrict__ w1h,
    const float* __restrict__ w2, const float* __restrict__ rsw,
    unsigned short* __restrict__ w2h,
    const float* __restrict__ pcoords, const float* __restrict__ lnw,
    const float* __restrict__ lnb, const float* __restrict__ pgauss,
    const float* __restrict__ pemb_w, const float* __restrict__ nap,
    const int* __restrict__ plabels, unsigned short* __restrict__ xnh)
{
  const int N1 = DIP*CDIM/4;
  const int N2 = CDIM*DI/4;
  const int NBW = (N1 + N2 + 255)/256;
  int bid = blockIdx.x;
  int t = threadIdx.x;

  if (bid < NBW) {   // role A: weight conversion
    int i4 = bid*256 + t;
    if (i4 < N1) {
      float4 v = ((const float4*)w1)[i4];
      unsigned short o[4] = {f2bf(v.x), f2bf(v.y), f2bf(v.z), f2bf(v.w)};
      *(uint2*)&w1h[i4*4] = *(const uint2*)o;
    } else if (i4 - N1 < N2) {
      int j = i4 - N1;
      float4 v = ((const float4*)w2)[j];
      float4 wv = *(const float4*)(rsw + (j*4) % DI);
      unsigned short o[4] = {f2bf(v.x*wv.x), f2bf(v.y*wv.y),
                             f2bf(v.z*wv.z), f2bf(v.w*wv.w)};
      *(uint2*)&w2h[j*4] = *(const uint2*)o;
    }
    return;
  }
  bid -= NBW;        // role C: point tokens + LN (one block per (b,j))
  int j = bid & 7, b = bid >> 3;
  float p0 = pcoords[(b*8+j)*3+0]*(2.0f/16.0f) - 1.0f;
  float p1 = pcoords[(b*8+j)*3+1]*(2.0f/16.0f) - 1.0f;
  float p2 = pcoords[(b*8+j)*3+2]*(2.0f/16.0f) - 1.0f;
  int lab = plabels[b*8+j];
  int safe = lab < 0 ? 0 : (lab > 1 ? 1 : lab);
  float vA, vB = 0.f;
  {
    int cc = t;
    int f = (cc < 160) ? cc : cc - 160;
    float pe = 6.283185307179586f*(p0*pgauss[f] + p1*pgauss[160+f] + p2*pgauss[320+f]);
    float pv = (cc < 160) ? sinf(pe) : cosf(pe);
    vA = (lab == -1) ? nap[cc] : pv + pemb_w[safe*CDIM + cc];
  }
  if (t < 64) {
    int cc = t + 256;
    int f = cc - 160;
    float pe = 6.283185307179586f*(p0*pgauss[f] + p1*pgauss[160+f] + p2*pgauss[320+f]);
    float pv = cosf(pe);
    vB = (lab == -1) ? nap[cc] : pv + pemb_w[safe*CDIM + cc];
  }
  float s  = warp_sum(vA + vB);
  float s2 = warp_sum(vA*vA + vB*vB);
  __shared__ float r1[4], r2[4];
  int w = t >> 6, lane = t & 63;
  if (lane == 0) { r1[w] = s; r2[w] = s2; }
  __syncthreads();
  float ts  = r1[0]+r1[1]+r1[2]+r1[3];
  float ts2 = r2[0]+r2[1]+r2[2]+r2[3];
  float mu   = ts * (1.0f/CDIM);
  float rsig = rsqrtf(ts2*(1.0f/CDIM) - mu*mu + 1e-5f);
  size_t base = ((size_t)b*LQ + NTQ + j)*CDIM;
  xnh[base + t] = f2bf((vA - mu)*rsig*lnw[t] + lnb[t]);
  if (t < 64)
    xnh[base + t + 256] = f2bf((vB - mu)*rsig*lnw[t+256] + lnb[t+256]);
}

// ---------------- K1: single-pass LayerNorm, f32 LDS cache (x read ONCE) ----------------
__global__ __launch_bounds__(256) void k_ln(
    const float* __restrict__ x, const float* __restrict__ lnw,
    const float* __restrict__ lnb, unsigned short* __restrict__ xnh)
{
  int b = blockIdx.y;
  int t0 = blockIdx.x * 32;
  int t = threadIdx.x;
  int lt = t & 31, cg = t >> 5;      // 8 channel groups x 32 tokens
  const float* xb = x + ((size_t)b*CDIM)*NTQ;

  __shared__ float XC[CDIM][33];     // f32 cache: 42 KB
  __shared__ float sA[8][32], s2A[8][32];
  __shared__ float muL[32], rsL[32];

  float s = 0.f, s2 = 0.f;
  for (int c = cg; c < CDIM; c += 8) {
    float v = xb[(size_t)c*NTQ + t0 + lt];
    s += v; s2 = fmaf(v, v, s2);
    XC[c][lt] = v;
  }
  sA[cg][lt] = s; s2A[cg][lt] = s2;
  __syncthreads();
  if (t < 32) {
    float ts = 0.f, ts2 = 0.f;
    #pragma unroll
    for (int g = 0; g < 8; g++) { ts += sA[g][t]; ts2 += s2A[g][t]; }
    float mu = ts*(1.0f/CDIM);
    muL[t] = mu;
    rsL[t] = rsqrtf(ts2*(1.0f/CDIM) - mu*mu + 1e-5f);
  }
  __syncthreads();
  #pragma unroll
  for (int it = 0; it < 10; it++) {
    int idx = t + it*256;            // 32 tok x 80 quad-groups
    int tok = idx / 80, g4 = idx % 80;
    int c0 = g4*4;
    float mu = muL[tok], rs = rsL[tok];
    float4 wv = *(const float4*)(lnw + c0);
    float4 bv = *(const float4*)(lnb + c0);
    unsigned short o[4];
    o[0] = f2bf((XC[c0+0][tok] - mu)*rs*wv.x + bv.x);
    o[1] = f2bf((XC[c0+1][tok] - mu)*rs*wv.y + bv.y);
    o[2] = f2bf((XC[c0+2][tok] - mu)*rs*wv.z + bv.z);
    o[3] = f2bf((XC[c0+3][tok] - mu)*rs*wv.w + bv.w);
    *(uint2*)&xnh[((size_t)(b*LQ) + t0 + tok)*CDIM + c0] = *(const uint2*)o;
  }
}

// ---------------- K2: zxh = xn @ w1^T, dbuf pipeline + LDS-bounced coalesced stores ----------------
__global__ __launch_bounds__(256) void k_gemm1_mfma(
    const unsigned short* __restrict__ Abf, const unsigned short* __restrict__ Wbf,
    unsigned short* __restrict__ zxh, float* __restrict__ dtraw)
{
  __shared__ unsigned short SM[16384];   // As0|As1|Bs0|Bs1 ; epilogue: 128x128 out tile
#define AS1(buf) (SM + (buf)*4096)
#define BS1(buf) (SM + 8192 + (buf)*4096)
  int id = blockIdx.x;
  int xcd = id & 7, pos = id >> 3;
  const int q = 177, r = 3;
  int swz = (xcd < r ? xcd*(q+1) : r*(q+1) + (xcd-r)*q) + pos;
  int m0 = (swz / 11) * 128;
  int n0 = (swz % 11) * 128;
  int tid = threadIdx.x;
  int lane = tid & 63, wid = tid >> 6;
  int wr = wid >> 1, wc = wid & 1;
  int fr = lane & 15, fq = lane >> 4;
  int srow = lane >> 2;
  int scol = (lane & 3) * 8;

#define G1_STAGE(buf, kk)                                                   \
  {                                                                         \
    _Pragma("unroll")                                                       \
    for (int i = 0; i < 2; i++) {                                           \
      int seg = wid + i*4;                                                  \
      int rowA = seg*16 + srow;                                             \
      int ga = m0 + rowA; if (ga > MQ-1) ga = MQ-1;                         \
      gload16(Abf + (size_t)ga*CDIM + (kk) + scol, AS1(buf) + seg*512);     \
      int gb = n0 + rowA; if (gb > DIP-1) gb = DIP-1;                       \
      gload16(Wbf + (size_t)gb*CDIM + (kk) + scol, BS1(buf) + seg*512);     \
    }                                                                       \
  }

#define G1_COMPUTE(buf)                                                     \
  {                                                                         \
    bf16x8 fa[4], fb[4];                                                    \
    _Pragma("unroll")                                                       \
    for (int i = 0; i < 4; i++) {                                           \
      fa[i] = *(const bf16x8*)(AS1(buf) + (wr*64 + i*16 + fr)*32 + fq*8);   \
      fb[i] = *(const bf16x8*)(BS1(buf) + (wc*64 + i*16 + fr)*32 + fq*8);   \
    }                                                                       \
    _Pragma("unroll")                                                       \
    for (int i = 0; i < 4; i++)                                             \
      _Pragma("unroll")                                                     \
      for (int j = 0; j < 4; j++)                                           \
        acc[i][j] = __builtin_amdgcn_mfma_f32_16x16x32_bf16(fa[i], fb[j], acc[i][j], 0, 0, 0); \
  }

  f32x4 acc[4][4] = {};
  G1_STAGE(0, 0);
  __syncthreads();
  int cur = 0;
  for (int k0 = 32; k0 < CDIM; k0 += 32) {
    G1_STAGE(cur^1, k0);
    G1_COMPUTE(cur);
    __syncthreads();
    cur ^= 1;
  }
  G1_COMPUTE(cur);
  __syncthreads();   // all LDS reads done; SM now reusable as output tile

  // fragments -> SM with group swizzle gs = (g + 2*fq) & 15
  #pragma unroll
  for (int i = 0; i < 4; i++) {
    #pragma unroll
    for (int j = 0; j < 4; j++) {
      #pragma unroll
      for (int rr = 0; rr < 4; rr++) {
        int rowL = wr*64 + i*16 + fq*4 + rr;
        int colL = wc*64 + j*16 + fr;
        float v = acc[i][j][rr];
        int gcol = n0 + colL;
        // gcol < DIP guard is essential (last-tile clamped fragments)
        if (gcol >= DI + CONVD && gcol < DIP && m0 + rowL < MQ)
          dtraw[(size_t)(m0+rowL)*NH + (gcol - (DI + CONVD))] = v;
        int g = colL >> 3;
        int gs = (g + 2*fq) & 15;
        SM[rowL*128 + gs*8 + (colL & 7)] = f2bf(v);
      }
    }
  }
  __syncthreads();
  int rows = MQ - m0; if (rows > 128) rows = 128;
  int cols = DIP - n0; if (cols > 128) cols = 128;   // 72 on last n-tile
  #pragma unroll
  for (int it = 0; it < 8; it++) {
    int idx = tid + it*256;
    int row = idx >> 4, g = idx & 15;
    int fqr = (row >> 2) & 3;
    int gs = (g + 2*fqr) & 15;
    if (row < rows && g*8 < cols)
      *(uint4*)&zxh[(size_t)(m0+row)*DIP + n0 + g*8] = *(const uint4*)&SM[row*128 + gs*8];
  }
}

// ---------------- K4: depthwise causal conv(4) + SiLU, register-tiled x8 tokens ----------------
__global__ __launch_bounds__(256) void k_conv(
    const unsigned short* __restrict__ zxh, const float* __restrict__ cw,
    const float* __restrict__ cb, unsigned short* __restrict__ xcb)
{
  const int nC4 = CONVD/4;
  int gid = blockIdx.x*256 + threadIdx.x;
  if (gid >= (MQ/8)*nC4) return;
  int c4 = gid % nC4;
  int mb = gid / nC4;
  int m0 = mb*8;
  int l0 = m0 % LQ;
  int c0 = c4*4;
  float4 cbv = *(const float4*)(cb + c0);
  float4 w0 = *(const float4*)(cw + (c0+0)*4);
  float4 w1 = *(const float4*)(cw + (c0+1)*4);
  float4 w2 = *(const float4*)(cw + (c0+2)*4);
  float4 w3 = *(const float4*)(cw + (c0+3)*4);
  const float* wp[4] = {(const float*)&w0, (const float*)&w1,
                        (const float*)&w2, (const float*)&w3};
  float vals[11][4];
  #pragma unroll
  for (int r = 0; r < 11; r++) {
    int ls = l0 - 3 + r;
    uint2 u = make_uint2(0,0);
    if (ls >= 0)
      u = *(const uint2*)(zxh + (size_t)(m0-3+r)*DIP + DI + c0);
    vals[r][0] = bf2f((unsigned short)(u.x & 0xffff));
    vals[r][1] = bf2f((unsigned short)(u.x >> 16));
    vals[r][2] = bf2f((unsigned short)(u.y & 0xffff));
    vals[r][3] = bf2f((unsigned short)(u.y >> 16));
  }
  const float* cbp = (const float*)&cbv;
  #pragma unroll
  for (int u = 0; u < 8; u++) {
    unsigned short o[4];
    #pragma unroll
    for (int ch = 0; ch < 4; ch++) {
      float a = cbp[ch];
      #pragma unroll
      for (int j = 0; j < 4; j++)
        a = fmaf(vals[u+j][ch], wp[ch][j], a);
      o[ch] = f2bf(a / (1.f + __expf(-a)));
    }
    *(uint2*)(xcb + (size_t)(m0+u)*CONVD + c0) = *(const uint2*)o;
  }
}

// ---------------- K5ab: fused softplus + in-wave cumsum + chunk end-state MFMA ----------------
__global__ __launch_bounds__(256) void k_cumsum_state(
    const float* __restrict__ dtraw, const float* __restrict__ dt_bias,
    const float* __restrict__ A_log, const unsigned short* __restrict__ xcb,
    float* __restrict__ dtb, float* __restrict__ cs, float* __restrict__ Dc,
    float* __restrict__ Sbuf)
{
  int c = blockIdx.x, h = blockIdx.y, b = blockIdx.z;
  int len = LQ - c*QC; if (len > QC) len = QC;
  int t = threadIdx.x;
  int lane = t & 63, wid = t >> 6;
  int fr = lane & 15, fq = lane >> 4;
  int m0 = b*LQ + c*QC;

  __shared__ unsigned short XT[HD*QC];
  __shared__ unsigned short BwT[DS*QC];
  __shared__ float ws[QC];

  for (int idx = t; idx < (HD/8)*QC; idx += 256) {
    int pg = idx % 10, i = idx / 10;
    uint4 v = make_uint4(0,0,0,0);
    if (i < len)
      v = *(const uint4*)(xcb + (size_t)(m0+i)*CONVD + h*HD + pg*8);
    union { uint4 u; unsigned short us[8]; } cv; cv.u = v;
    #pragma unroll
    for (int e = 0; e < 8; e++)
      XT[swz64(pg*8+e, i)] = cv.us[e];
  }

  if (t < QC) {
    float A = -expf(A_log[h]);
    float sp = 0.f;
    if (t < len) {
      float v = dtraw[((size_t)(m0+t))*NH + h] + dt_bias[h];
      sp = (v > 20.f) ? v : log1pf(expf(v));
      dtb[((size_t)(m0+t))*NH + h] = sp;
    }
    float a = sp * A;
    #pragma unroll
    for (int off = 1; off < 64; off <<= 1) {
      float pv = __shfl_up(a, off, 64);
      if (t >= off) a += pv;
    }
    cs[((size_t)(b*NH+h)*NC + c)*QC + t] = a;
    if (t == len-1) Dc[(b*NH+h)*NC + c] = expf(a);
    float aEnd = __shfl(a, len-1, 64);
    ws[t] = (t < len) ? __expf(aEnd - a) * sp : 0.f;
  }
  __syncthreads();
  for (int idx = t; idx < DS*QC; idx += 256) {
    int n = idx & 31, i = idx >> 5;
    float v = (i < len) ? bf2f(xcb[(size_t)(m0+i)*CONVD + DI + n]) * ws[i] : 0.f;
    BwT[swz64(n, i)] = f2bf(v);
  }
  __syncthreads();

  size_t base = ((size_t)(b*NC + c)*NH + h)*(HD*DS);
  for (int tp = wid; tp < 10; tp += 4) {
    int pi = tp >> 1, ni = tp & 1;
    f32x4 acc = {};
    #pragma unroll
    for (int ks = 0; ks < 2; ks++) {
      bf16x8 fa = *(const bf16x8*)&XT[swz64(pi*16 + fr, ks*32 + fq*8)];
      bf16x8 fb = *(const bf16x8*)&BwT[swz64(ni*16 + fr, ks*32 + fq*8)];
      acc = __builtin_amdgcn_mfma_f32_16x16x32_bf16(fa, fb, acc, 0, 0, 0);
    }
    #pragma unroll
    for (int rr = 0; rr < 4; rr++)
      Sbuf[base + (size_t)(pi*16 + fq*4 + rr)*DS + ni*16 + fr] = acc[rr];
  }
}

// ---------------- K5c: sequential scan over chunk states, bf16 H0 out ----------------
__global__ __launch_bounds__(256) void k_state_scan(
    const float* __restrict__ Sbuf, const float* __restrict__ Dc,
    unsigned short* __restrict__ H0h)
{
  int tid = blockIdx.x*256 + threadIdx.x;
  int pn = tid % (HD*DS);
  int bh = tid / (HD*DS);
  int b = bh >> 3, h = bh & 7;
  float hst = 0.f;
  for (int c = 0; c < NC; c++) {
    size_t idx = ((size_t)(b*NC + c)*NH + h)*(HD*DS) + pn;
    float sv = Sbuf[idx];
    H0h[idx] = f2bf(hst);
    hst = hst * Dc[bh*NC + c] + sv;
  }
}

// ---------------- K5d: per-chunk outputs (QC=64) + ssum8 partials ----------------
__global__ __launch_bounds__(256) void k_chunk_y_mfma(
    const unsigned short* __restrict__ xcb, const unsigned short* __restrict__ zxh,
    const float* __restrict__ dtb, const float* __restrict__ cs,
    const unsigned short* __restrict__ H0h, const float* __restrict__ Dp,
    unsigned short* __restrict__ ygb, float* __restrict__ ssum8)
{
  int c = blockIdx.x, h = blockIdx.y, b = blockIdx.z;
  int len = LQ - c*QC; if (len > QC) len = QC;
  int t = threadIdx.x;
  int lane = t & 63, wid = t >> 6;
  int fr = lane & 15, fq = lane >> 4;
  int m0 = b*LQ + c*QC;

  __shared__ unsigned short XT[HD*QC];
  __shared__ unsigned short Wt[4*16*32];
  __shared__ float slA[QC], dtlA[QC], elA[QC];

  const float* csb = cs + ((size_t)(b*NH+h)*NC + c)*QC;

  for (int idx = t; idx < (HD/8)*QC; idx += 256) {
    int pg = idx % 10, i = idx / 10;
    uint4 v = make_uint4(0,0,0,0);
    if (i < len)
      v = *(const uint4*)(xcb + (size_t)(m0+i)*CONVD + h*HD + pg*8);
    union { uint4 u; unsigned short us[8]; } cv; cv.u = v;
    #pragma unroll
    for (int e = 0; e < 8; e++)
      XT[swz64(pg*8+e, i)] = cv.us[e];
  }
  if (t < QC) {
    float s = csb[t];
    slA[t] = s;
    elA[t] = __expf(s);
    dtlA[t] = (t < len) ? dtb[((size_t)(m0+t))*NH + h] : 0.f;
  }
  __syncthreads();

  int row16 = wid*16 + fr;
  bf16x8 fa = {};
  if (row16 < len)
    fa = *(const bf16x8*)(xcb + (size_t)(m0+row16)*CONVD + DI + DS + fq*8);

  size_t hb = ((size_t)(b*NC + c)*NH + h)*(HD*DS);
  f32x4 acc[5];
  #pragma unroll
  for (int j = 0; j < 5; j++) {
    int p = j*16 + fr;
    bf16x8 fb = *(const bf16x8*)(H0h + hb + (size_t)p*DS + fq*8);
    f32x4 z = {};
    acc[j] = __builtin_amdgcn_mfma_f32_16x16x32_bf16(fa, fb, z, 0, 0, 0);
  }
  #pragma unroll
  for (int rr = 0; rr < 4; rr++) {
    float el = elA[wid*16 + fq*4 + rr];
    #pragma unroll
    for (int j = 0; j < 5; j++) acc[j][rr] *= el;
  }

  int wbase = wid << 9;
  for (int sc = 0; sc < 2; sc++) {
    int i0 = sc*32;
    #pragma unroll
    for (int jt = 0; jt < 2; jt++) {
      int col = i0 + jt*16 + fr;
      bf16x8 fbv = {};
      if (col < len)
        fbv = *(const bf16x8*)(xcb + (size_t)(m0+col)*CONVD + DI + fq*8);
      float sc_col = slA[col], dt_col = dtlA[col];
      f32x4 z = {};
      f32x4 g = __builtin_amdgcn_mfma_f32_16x16x32_bf16(fa, fbv, z, 0, 0, 0);
      #pragma unroll
      for (int rr = 0; rr < 4; rr++) {
        int lr = fq*4 + rr;
        int row = wid*16 + lr;
        float v = 0.f;
        if (col <= row)
          v = g[rr] * __expf(slA[row] - sc_col) * dt_col;
        int lc = jt*16 + fr;
        int slot = (lc >> 3) ^ (lr & 3);
        Wt[wbase + (lr<<5) + (slot<<3) + (lc&7)] = f2bf(v);
      }
    }
    bf16x8 wa = *(const bf16x8*)&Wt[wbase + (fr<<5) + ((fq ^ (fr&3))<<3)];
    #pragma unroll
    for (int j = 0; j < 5; j++) {
      int p = j*16 + fr;
      bf16x8 xb = *(const bf16x8*)&XT[swz64(p, i0 + fq*8)];
      acc[j] = __builtin_amdgcn_mfma_f32_16x16x32_bf16(wa, xb, acc[j], 0, 0, 0);
    }
  }

  float dpv = Dp[h];
  #pragma unroll
  for (int rr = 0; rr < 4; rr++) {
    int l = wid*16 + fq*4 + rr;
    if (l >= len) continue;
    size_t m = m0 + l;
    float ssp = 0.f;
    #pragma unroll
    for (int j = 0; j < 5; j++) {
      int p = j*16 + fr;
      int cc = h*HD + p;
      float xv = bf2f(XT[swz64(p, l)]);
      float y = acc[j][rr] + xv*dpv;
      float zv = bf2f(zxh[m*DIP + cc]);
      y *= zv / (1.f + __expf(-zv));
      ygb[m*DI + cc] = f2bf(y);
      ssp = fmaf(y, y, ssp);
    }
    #pragma unroll
    for (int o = 1; o < 16; o <<= 1) ssp += __shfl_xor(ssp, o);
    if (fr == 0) ssum8[m*NH + h] = ssp;
  }
}

// ---------------- K7: out^T = (w2*rsw) @ ygb^T, rsv in epilogue ----------------
__global__ __launch_bounds__(256) void k_gemm2_mfma(
    const unsigned short* __restrict__ W2h, const unsigned short* __restrict__ Ygh,
    const float* __restrict__ ssum8, float* __restrict__ out)
{
  __shared__ unsigned short As[2][128*32];
  __shared__ unsigned short Bs[2][128*32];
  int id = blockIdx.x;
  int xcd = id & 7, pos = id >> 3;
  const int q = 48, r = 3;
  int swz = (xcd < r ? xcd*(q+1) : r*(q+1) + (xcd-r)*q) + pos;
  int c0 = (swz % 3) * 128;
  int t0 = (swz / 3) * 128;
  int tid = threadIdx.x;
  int lane = tid & 63, wid = tid >> 6;
  int wr = wid >> 1, wc = wid & 1;
  int fr = lane & 15, fq = lane >> 4;
  int srow = lane >> 2;
  int scol = (lane & 3) * 8;

#define G2_STAGE(buf, kk)                                                   \
  {                                                                         \
    _Pragma("unroll")                                                       \
    for (int i = 0; i < 2; i++) {                                           \
      int seg = wid + i*4;                                                  \
      int rowA = seg*16 + srow;                                             \
      int ga = c0 + rowA; if (ga > CDIM-1) ga = CDIM-1;                     \
      gload16(W2h + (size_t)ga*DI + (kk) + scol, &As[buf][seg*512]);        \
      int gb = t0 + rowA; if (gb > MQ-1) gb = MQ-1;                         \
      gload16(Ygh + (size_t)gb*DI + (kk) + scol, &Bs[buf][seg*512]);        \
    }                                                                       \
  }

#define G2_COMPUTE(buf)                                                     \
  {                                                                         \
    bf16x8 fa[4], fb[4];                                                    \
    _Pragma("unroll")                                                       \
    for (int i = 0; i < 4; i++) {                                           \
      fa[i] = *(const bf16x8*)&As[buf][(wr*64 + i*16 + fr)*32 + fq*8];      \
      fb[i] = *(const bf16x8*)&Bs[buf][(wc*64 + i*16 + fr)*32 + fq*8];      \
    }                                                                       \
    _Pragma("unroll")                                                       \
    for (int i = 0; i < 4; i++)                                             \
      _Pragma("unroll")                                                     \
      for (int j = 0; j < 4; j++)                                           \
        acc[i][j] = __builtin_amdgcn_mfma_f32_16x16x32_bf16(fa[i], fb[j], acc[i][j], 0, 0, 0); \
  }

  f32x4 acc[4][4] = {};
  G2_STAGE(0, 0);
  __syncthreads();
  int cur = 0;
  for (int k0 = 32; k0 < DI; k0 += 32) {
    G2_STAGE(cur^1, k0);
    G2_COMPUTE(cur);
    __syncthreads();
    cur ^= 1;
  }
  G2_COMPUTE(cur);

  float rsvj[4];
  #pragma unroll
  for (int j = 0; j < 4; j++) {
    int tok = t0 + wc*64 + j*16 + fr;
    float ss = 0.f;
    if (tok < MQ) {
      float4 a = *(const float4*)(ssum8 + (size_t)tok*NH);
      float4 bb = *(const float4*)(ssum8 + (size_t)tok*NH + 4);
      ss = (a.x + a.y + a.z + a.w) + (bb.x + bb.y + bb.z + bb.w);
    }
    rsvj[j] = rsqrtf(ss*(1.0f/DI) + 1e-5f);
  }

  #pragma unroll
  for (int i = 0; i < 4; i++) {
    #pragma unroll
    for (int j = 0; j < 4; j++) {
      #pragma unroll
      for (int rr = 0; rr < 4; rr++) {
        int ch  = c0 + wr*64 + i*16 + fq*4 + rr;
        int tok = t0 + wc*64 + j*16 + fr;
        if (ch < CDIM && tok < MQ) {
          int b = tok / LQ, l = tok % LQ;
          if (l < NTQ)
            out[((size_t)(b*CDIM + ch))*NTQ + l] = acc[i][j][rr] * rsvj[j];
        }
      }
    }
  }
}

extern "C" void kernel_launch(void* const* d_in, const int* in_sizes, int n_in,
                              void* d_out, int out_size, void* d_ws, size_t ws_size,
                              hipStream_t stream)
{
  const float* x       = (const float*)d_in[0];
  const float* pc      = (const float*)d_in[1];
  const float* lnw     = (const float*)d_in[2];
  const float* lnb     = (const float*)d_in[3];
  const float* w1      = (const float*)d_in[4];
  const float* cw      = (const float*)d_in[5];
  const float* cb      = (const float*)d_in[6];
  const float* dt_bias = (const float*)d_in[7];
  const float* A_log   = (const float*)d_in[8];
  const float* Dp      = (const float*)d_in[9];
  const float* rsw     = (const float*)d_in[10];
  const float* w2      = (const float*)d_in[11];
  const float* pg      = (const float*)d_in[12];
  const float* pew     = (const float*)d_in[13];
  const float* nap     = (const float*)d_in[14];
  const int*   plab    = (const int*)d_in[15];
  float* out = (float*)d_out;

  unsigned short* xnh  = (unsigned short*)d_ws;                     // MQ*CDIM bf16
  unsigned short* zxh  = xnh + (size_t)MQ*CDIM;                     // MQ*DIP bf16
  float* dtraw = (float*)(zxh + (size_t)MQ*DIP);                    // MQ*NH f32
  unsigned short* xcb  = (unsigned short*)(dtraw + (size_t)MQ*NH);  // MQ*CONVD bf16
  float* dtb = (float*)(xcb + (size_t)MQ*CONVD);                    // MQ*NH f32
  float* cs  = dtb + (size_t)MQ*NH;                                 // B*NH*NC*QC
  float* Dc  = cs  + (size_t)BQ*NH*NC*QC;                           // B*NH*NC
  float* Sb  = Dc  + (size_t)BQ*NH*NC;                              // B*NC*NH*HD*DS f32
  unsigned short* H0h = (unsigned short*)(Sb + (size_t)BQ*NC*NH*HD*DS);
  unsigned short* ygb = H0h + (size_t)BQ*NC*NH*HD*DS;               // MQ*DI bf16
  unsigned short* w1h = ygb + (size_t)MQ*DI;                        // DIP*CDIM bf16
  unsigned short* w2h = w1h + (size_t)DIP*CDIM;                     // CDIM*DI bf16 (rsw folded)
  float* ssum8 = (float*)(w2h + (size_t)CDIM*DI);                   // MQ*NH f32

  const int NBW = (DIP*CDIM/4 + CDIM*DI/4 + 255)/256;
  k_prep<<<NBW + 32, 256, 0, stream>>>(
      w1, w1h, w2, rsw, w2h,
      pc, lnw, lnb, pg, pew, nap, plab, xnh);
  dim3 gl(NTQ/32, BQ);
  k_ln<<<gl, 256, 0, stream>>>(x, lnw, lnb, xnh);
  k_gemm1_mfma<<<129*11, 256, 0, stream>>>(xnh, w1h, zxh, dtraw);
  k_conv<<<((MQ/8)*(CONVD/4) + 255)/256, 256, 0, stream>>>(zxh, cw, cb, xcb);
  dim3 gc(NC, NH, BQ);
  k_cumsum_state<<<gc, 256, 0, stream>>>(dtraw, dt_bias, A_log, xcb, dtb, cs, Dc, Sb);
  k_state_scan<<<(BQ*NH*HD*DS)/256, 256, 0, stream>>>(Sb, Dc, H0h);
  k_chunk_y_mfma<<<gc, 256, 0, stream>>>(xcb, zxh, dtb, cs, H0h, Dp, ygb, ssum8);
  k_gemm2_mfma<<<129*3, 256, 0, stream>>>(w2h, ygb, ssum8, out);
}

// Round 16
// 145.056 us; speedup vs baseline: 1.0678x; 1.0678x over previous
//
#include <hip/hip_runtime.h>
#include <math.h>

#define BQ 4
#define LQ 4104
#define NTQ 4096
#define CDIM 320
#define DIP 1352
#define DI 640
#define CONVD 704
#define NH 8
#define HD 80
#define DS 32
#define MQ (BQ*LQ)   // 16416
#define QC 64        // chunk length
#define NC 65        // ceil(LQ/QC)

typedef __attribute__((ext_vector_type(8))) short bf16x8;
typedef __attribute__((ext_vector_type(4))) float f32x4;

__device__ __forceinline__ unsigned short f2bf(float f){
  union { float f; unsigned u; } v; v.f = f;
  unsigned r = v.u + 0x7FFFu + ((v.u >> 16) & 1u);
  return (unsigned short)(r >> 16);
}
__device__ __forceinline__ float bf2f(unsigned short u){
  union { unsigned u; float f; } v; v.u = ((unsigned)u) << 16;
  return v.f;
}
__device__ __forceinline__ float warp_sum(float v){
  #pragma unroll
  for (int o = 32; o; o >>= 1) v += __shfl_xor(v, o);
  return v;
}
__device__ __forceinline__ void gload16(const unsigned short* g, unsigned short* l){
  __builtin_amdgcn_global_load_lds(
      (const __attribute__((address_space(1))) unsigned int*)g,
      (__attribute__((address_space(3))) unsigned int*)l, 16, 0, 0);
}
__device__ __forceinline__ int swz64(int p, int i){
  return p*QC + (i ^ ((p & 7) << 3));
}

// ---------------- K0: fused prologue: weight converts (rsw folded into w2) +
//                   LN stats partials + point-token LN ----------------
__global__ __launch_bounds__(256) void k_prep(
    const float* __restrict__ w1, unsigned short* __restrict__ w1h,
    const float* __restrict__ w2, const float* __restrict__ rsw,
    unsigned short* __restrict__ w2h,
    const float* __restrict__ x, float* __restrict__ muP, float* __restrict__ s2P,
    const float* __restrict__ pcoords, const float* __restrict__ lnw,
    const float* __restrict__ lnb, const float* __restrict__ pgauss,
    const float* __restrict__ pemb_w, const float* __restrict__ nap,
    const int* __restrict__ plabels, unsigned short* __restrict__ xnh)
{
  const int N1 = DIP*CDIM/4;
  const int N2 = CDIM*DI/4;
  const int NBW = (N1 + N2 + 255)/256;
  int bid = blockIdx.x;
  int t = threadIdx.x;

  if (bid < NBW) {   // role A: weight conversion
    int i4 = bid*256 + t;
    if (i4 < N1) {
      float4 v = ((const float4*)w1)[i4];
      unsigned short o[4] = {f2bf(v.x), f2bf(v.y), f2bf(v.z), f2bf(v.w)};
      *(uint2*)&w1h[i4*4] = *(const uint2*)o;
    } else if (i4 - N1 < N2) {
      int j = i4 - N1;
      float4 v = ((const float4*)w2)[j];
      float4 wv = *(const float4*)(rsw + (j*4) % DI);
      unsigned short o[4] = {f2bf(v.x*wv.x), f2bf(v.y*wv.y),
                             f2bf(v.z*wv.z), f2bf(v.w*wv.w)};
      *(uint2*)&w2h[j*4] = *(const uint2*)o;
    }
    return;
  }
  bid -= NBW;
  if (bid < 512) {   // role B: LN stats partials (8 channel-slices)
    int xblk = bid & 15, sl = (bid >> 4) & 7, b = bid >> 7;
    int cs0 = sl * 40;
    int tok = xblk*256 + t;
    const float* xb = x + ((size_t)b*CDIM)*NTQ;
    float s = 0.f, s2 = 0.f;
    #pragma unroll 8
    for (int c = cs0; c < cs0 + 40; c++) {
      float v = xb[(size_t)c*NTQ + tok];
      s += v; s2 = fmaf(v, v, s2);
    }
    muP[((size_t)sl*BQ + b)*NTQ + tok] = s;
    s2P[((size_t)sl*BQ + b)*NTQ + tok] = s2;
    return;
  }
  bid -= 512;        // role C: point tokens + LN (one block per (b,j))
  int j = bid & 7, b = bid >> 3;
  float p0 = pcoords[(b*8+j)*3+0]*(2.0f/16.0f) - 1.0f;
  float p1 = pcoords[(b*8+j)*3+1]*(2.0f/16.0f) - 1.0f;
  float p2 = pcoords[(b*8+j)*3+2]*(2.0f/16.0f) - 1.0f;
  int lab = plabels[b*8+j];
  int safe = lab < 0 ? 0 : (lab > 1 ? 1 : lab);
  float vA, vB = 0.f;
  {
    int cc = t;
    int f = (cc < 160) ? cc : cc - 160;
    float pe = 6.283185307179586f*(p0*pgauss[f] + p1*pgauss[160+f] + p2*pgauss[320+f]);
    float pv = (cc < 160) ? sinf(pe) : cosf(pe);
    vA = (lab == -1) ? nap[cc] : pv + pemb_w[safe*CDIM + cc];
  }
  if (t < 64) {
    int cc = t + 256;
    int f = cc - 160;
    float pe = 6.283185307179586f*(p0*pgauss[f] + p1*pgauss[160+f] + p2*pgauss[320+f]);
    float pv = cosf(pe);
    vB = (lab == -1) ? nap[cc] : pv + pemb_w[safe*CDIM + cc];
  }
  float s  = warp_sum(vA + vB);
  float s2 = warp_sum(vA*vA + vB*vB);
  __shared__ float r1[4], r2[4];
  int w = t >> 6, lane = t & 63;
  if (lane == 0) { r1[w] = s; r2[w] = s2; }
  __syncthreads();
  float ts  = r1[0]+r1[1]+r1[2]+r1[3];
  float ts2 = r2[0]+r2[1]+r2[2]+r2[3];
  float mu   = ts * (1.0f/CDIM);
  float rsig = rsqrtf(ts2*(1.0f/CDIM) - mu*mu + 1e-5f);
  size_t base = ((size_t)b*LQ + NTQ + j)*CDIM;
  xnh[base + t] = f2bf((vA - mu)*rsig*lnw[t] + lnb[t]);
  if (t < 64)
    xnh[base + t + 256] = f2bf((vB - mu)*rsig*lnw[t+256] + lnb[t+256]);
}

// ---------------- K1b: normalize + transpose -> xnh bf16 ----------------
__global__ __launch_bounds__(256) void k_norm_t(
    const float* __restrict__ x, const float* __restrict__ muP,
    const float* __restrict__ s2P, const float* __restrict__ lnw,
    const float* __restrict__ lnb, unsigned short* __restrict__ xnh)
{
  int b = blockIdx.z;
  int c0 = blockIdx.y * 64;
  int t0 = blockIdx.x * 64;
  int t = threadIdx.x;
  int lt = t & 63, cg = t >> 6;
  const float* xb = x + ((size_t)b*CDIM)*NTQ;

  __shared__ unsigned short T[64][72];
  __shared__ float muL[64], rsL[64];
  if (t < 64) {
    float s = 0.f, s2 = 0.f;
    #pragma unroll
    for (int sl = 0; sl < 8; sl++) {
      s  += muP[((size_t)sl*BQ + b)*NTQ + t0 + t];
      s2 += s2P[((size_t)sl*BQ + b)*NTQ + t0 + t];
    }
    float mu = s*(1.0f/CDIM);
    muL[t] = mu;
    rsL[t] = rsqrtf(s2*(1.0f/CDIM) - mu*mu + 1e-5f);
  }
  __syncthreads();
  float mu = muL[lt], rs = rsL[lt];
  #pragma unroll
  for (int c = cg; c < 64; c += 4) {
    float v = xb[(size_t)(c0+c)*NTQ + t0 + lt];
    T[lt][c] = f2bf((v - mu)*rs*lnw[c0+c] + lnb[c0+c]);
  }
  __syncthreads();
  #pragma unroll
  for (int i = 0; i < 4; i++) {
    int idx = t + 256*i;
    int tok = idx >> 4, cq = idx & 15;
    *(uint2*)&xnh[((size_t)(b*LQ) + t0 + tok)*CDIM + c0 + cq*4] =
        *(const uint2*)&T[tok][cq*4];
  }
}

// ---------------- K2: zxh = xn @ w1^T, dbuf pipeline + LDS-bounced coalesced stores ----------------
__global__ __launch_bounds__(256) void k_gemm1_mfma(
    const unsigned short* __restrict__ Abf, const unsigned short* __restrict__ Wbf,
    unsigned short* __restrict__ zxh, float* __restrict__ dtraw)
{
  __shared__ unsigned short SM[16384];   // As0|As1|Bs0|Bs1 ; epilogue: 128x128 out tile
#define AS1(buf) (SM + (buf)*4096)
#define BS1(buf) (SM + 8192 + (buf)*4096)
  int id = blockIdx.x;
  int xcd = id & 7, pos = id >> 3;
  const int q = 177, r = 3;
  int swz = (xcd < r ? xcd*(q+1) : r*(q+1) + (xcd-r)*q) + pos;
  int m0 = (swz / 11) * 128;
  int n0 = (swz % 11) * 128;
  int tid = threadIdx.x;
  int lane = tid & 63, wid = tid >> 6;
  int wr = wid >> 1, wc = wid & 1;
  int fr = lane & 15, fq = lane >> 4;
  int srow = lane >> 2;
  int scol = (lane & 3) * 8;

#define G1_STAGE(buf, kk)                                                   \
  {                                                                         \
    _Pragma("unroll")                                                       \
    for (int i = 0; i < 2; i++) {                                           \
      int seg = wid + i*4;                                                  \
      int rowA = seg*16 + srow;                                             \
      int ga = m0 + rowA; if (ga > MQ-1) ga = MQ-1;                         \
      gload16(Abf + (size_t)ga*CDIM + (kk) + scol, AS1(buf) + seg*512);     \
      int gb = n0 + rowA; if (gb > DIP-1) gb = DIP-1;                       \
      gload16(Wbf + (size_t)gb*CDIM + (kk) + scol, BS1(buf) + seg*512);     \
    }                                                                       \
  }

#define G1_COMPUTE(buf)                                                     \
  {                                                                         \
    bf16x8 fa[4], fb[4];                                                    \
    _Pragma("unroll")                                                       \
    for (int i = 0; i < 4; i++) {                                           \
      fa[i] = *(const bf16x8*)(AS1(buf) + (wr*64 + i*16 + fr)*32 + fq*8);   \
      fb[i] = *(const bf16x8*)(BS1(buf) + (wc*64 + i*16 + fr)*32 + fq*8);   \
    }                                                                       \
    _Pragma("unroll")                                                       \
    for (int i = 0; i < 4; i++)                                             \
      _Pragma("unroll")                                                     \
      for (int j = 0; j < 4; j++)                                           \
        acc[i][j] = __builtin_amdgcn_mfma_f32_16x16x32_bf16(fa[i], fb[j], acc[i][j], 0, 0, 0); \
  }

  f32x4 acc[4][4] = {};
  G1_STAGE(0, 0);
  __syncthreads();
  int cur = 0;
  for (int k0 = 32; k0 < CDIM; k0 += 32) {
    G1_STAGE(cur^1, k0);
    G1_COMPUTE(cur);
    __syncthreads();
    cur ^= 1;
  }
  G1_COMPUTE(cur);
  __syncthreads();   // all LDS reads done; SM now reusable as output tile

  // fragments -> SM with group swizzle gs = (g + 2*fq) & 15
  #pragma unroll
  for (int i = 0; i < 4; i++) {
    #pragma unroll
    for (int j = 0; j < 4; j++) {
      #pragma unroll
      for (int rr = 0; rr < 4; rr++) {
        int rowL = wr*64 + i*16 + fq*4 + rr;
        int colL = wc*64 + j*16 + fr;
        float v = acc[i][j][rr];
        int gcol = n0 + colL;
        // gcol < DIP guard is essential (last-tile clamped fragments)
        if (gcol >= DI + CONVD && gcol < DIP && m0 + rowL < MQ)
          dtraw[(size_t)(m0+rowL)*NH + (gcol - (DI + CONVD))] = v;
        int g = colL >> 3;
        int gs = (g + 2*fq) & 15;
        SM[rowL*128 + gs*8 + (colL & 7)] = f2bf(v);
      }
    }
  }
  __syncthreads();
  int rows = MQ - m0; if (rows > 128) rows = 128;
  int cols = DIP - n0; if (cols > 128) cols = 128;   // 72 on last n-tile
  #pragma unroll
  for (int it = 0; it < 8; it++) {
    int idx = tid + it*256;
    int row = idx >> 4, g = idx & 15;
    int fqr = (row >> 2) & 3;
    int gs = (g + 2*fqr) & 15;
    if (row < rows && g*8 < cols)
      *(uint4*)&zxh[(size_t)(m0+row)*DIP + n0 + g*8] = *(const uint4*)&SM[row*128 + gs*8];
  }
}

// ---------------- K4: depthwise causal conv(4) + SiLU, register-tiled x8 tokens ----------------
__global__ __launch_bounds__(256) void k_conv(
    const unsigned short* __restrict__ zxh, const float* __restrict__ cw,
    const float* __restrict__ cb, unsigned short* __restrict__ xcb)
{
  const int nC4 = CONVD/4;
  int gid = blockIdx.x*256 + threadIdx.x;
  if (gid >= (MQ/8)*nC4) return;
  int c4 = gid % nC4;
  int mb = gid / nC4;
  int m0 = mb*8;
  int l0 = m0 % LQ;
  int c0 = c4*4;
  float4 cbv = *(const float4*)(cb + c0);
  float4 w0 = *(const float4*)(cw + (c0+0)*4);
  float4 w1 = *(const float4*)(cw + (c0+1)*4);
  float4 w2 = *(const float4*)(cw + (c0+2)*4);
  float4 w3 = *(const float4*)(cw + (c0+3)*4);
  const float* wp[4] = {(const float*)&w0, (const float*)&w1,
                        (const float*)&w2, (const float*)&w3};
  float vals[11][4];
  #pragma unroll
  for (int r = 0; r < 11; r++) {
    int ls = l0 - 3 + r;
    uint2 u = make_uint2(0,0);
    if (ls >= 0)
      u = *(const uint2*)(zxh + (size_t)(m0-3+r)*DIP + DI + c0);
    vals[r][0] = bf2f((unsigned short)(u.x & 0xffff));
    vals[r][1] = bf2f((unsigned short)(u.x >> 16));
    vals[r][2] = bf2f((unsigned short)(u.y & 0xffff));
    vals[r][3] = bf2f((unsigned short)(u.y >> 16));
  }
  const float* cbp = (const float*)&cbv;
  #pragma unroll
  for (int u = 0; u < 8; u++) {
    unsigned short o[4];
    #pragma unroll
    for (int ch = 0; ch < 4; ch++) {
      float a = cbp[ch];
      #pragma unroll
      for (int j = 0; j < 4; j++)
        a = fmaf(vals[u+j][ch], wp[ch][j], a);
      o[ch] = f2bf(a / (1.f + __expf(-a)));
    }
    *(uint2*)(xcb + (size_t)(m0+u)*CONVD + c0) = *(const uint2*)o;
  }
}

// ---------------- K5ab: fused softplus + in-wave cumsum + chunk end-state MFMA ----------------
__global__ __launch_bounds__(256) void k_cumsum_state(
    const float* __restrict__ dtraw, const float* __restrict__ dt_bias,
    const float* __restrict__ A_log, const unsigned short* __restrict__ xcb,
    float* __restrict__ dtb, float* __restrict__ cs, float* __restrict__ Dc,
    float* __restrict__ Sbuf)
{
  int c = blockIdx.x, h = blockIdx.y, b = blockIdx.z;
  int len = LQ - c*QC; if (len > QC) len = QC;
  int t = threadIdx.x;
  int lane = t & 63, wid = t >> 6;
  int fr = lane & 15, fq = lane >> 4;
  int m0 = b*LQ + c*QC;

  __shared__ unsigned short XT[HD*QC];
  __shared__ unsigned short BwT[DS*QC];
  __shared__ float ws[QC];

  for (int idx = t; idx < (HD/8)*QC; idx += 256) {
    int pg = idx % 10, i = idx / 10;
    uint4 v = make_uint4(0,0,0,0);
    if (i < len)
      v = *(const uint4*)(xcb + (size_t)(m0+i)*CONVD + h*HD + pg*8);
    union { uint4 u; unsigned short us[8]; } cv; cv.u = v;
    #pragma unroll
    for (int e = 0; e < 8; e++)
      XT[swz64(pg*8+e, i)] = cv.us[e];
  }

  if (t < QC) {
    float A = -expf(A_log[h]);
    float sp = 0.f;
    if (t < len) {
      float v = dtraw[((size_t)(m0+t))*NH + h] + dt_bias[h];
      sp = (v > 20.f) ? v : log1pf(expf(v));
      dtb[((size_t)(m0+t))*NH + h] = sp;
    }
    float a = sp * A;
    #pragma unroll
    for (int off = 1; off < 64; off <<= 1) {
      float pv = __shfl_up(a, off, 64);
      if (t >= off) a += pv;
    }
    cs[((size_t)(b*NH+h)*NC + c)*QC + t] = a;
    if (t == len-1) Dc[(b*NH+h)*NC + c] = expf(a);
    float aEnd = __shfl(a, len-1, 64);
    ws[t] = (t < len) ? __expf(aEnd - a) * sp : 0.f;
  }
  __syncthreads();
  for (int idx = t; idx < DS*QC; idx += 256) {
    int n = idx & 31, i = idx >> 5;
    float v = (i < len) ? bf2f(xcb[(size_t)(m0+i)*CONVD + DI + n]) * ws[i] : 0.f;
    BwT[swz64(n, i)] = f2bf(v);
  }
  __syncthreads();

  size_t base = ((size_t)(b*NC + c)*NH + h)*(HD*DS);
  for (int tp = wid; tp < 10; tp += 4) {
    int pi = tp >> 1, ni = tp & 1;
    f32x4 acc = {};
    #pragma unroll
    for (int ks = 0; ks < 2; ks++) {
      bf16x8 fa = *(const bf16x8*)&XT[swz64(pi*16 + fr, ks*32 + fq*8)];
      bf16x8 fb = *(const bf16x8*)&BwT[swz64(ni*16 + fr, ks*32 + fq*8)];
      acc = __builtin_amdgcn_mfma_f32_16x16x32_bf16(fa, fb, acc, 0, 0, 0);
    }
    #pragma unroll
    for (int rr = 0; rr < 4; rr++)
      Sbuf[base + (size_t)(pi*16 + fq*4 + rr)*DS + ni*16 + fr] = acc[rr];
  }
}

// ---------------- K5c: sequential scan over chunk states, bf16 H0 out ----------------
__global__ __launch_bounds__(256) void k_state_scan(
    const float* __restrict__ Sbuf, const float* __restrict__ Dc,
    unsigned short* __restrict__ H0h)
{
  int tid = blockIdx.x*256 + threadIdx.x;
  int pn = tid % (HD*DS);
  int bh = tid / (HD*DS);
  int b = bh >> 3, h = bh & 7;
  float hst = 0.f;
  for (int c = 0; c < NC; c++) {
    size_t idx = ((size_t)(b*NC + c)*NH + h)*(HD*DS) + pn;
    float sv = Sbuf[idx];
    H0h[idx] = f2bf(hst);
    hst = hst * Dc[bh*NC + c] + sv;
  }
}

// ---------------- K5d: per-chunk outputs (QC=64) + ssum8 partials ----------------
__global__ __launch_bounds__(256) void k_chunk_y_mfma(
    const unsigned short* __restrict__ xcb, const unsigned short* __restrict__ zxh,
    const float* __restrict__ dtb, const float* __restrict__ cs,
    const unsigned short* __restrict__ H0h, const float* __restrict__ Dp,
    unsigned short* __restrict__ ygb, float* __restrict__ ssum8)
{
  int c = blockIdx.x, h = blockIdx.y, b = blockIdx.z;
  int len = LQ - c*QC; if (len > QC) len = QC;
  int t = threadIdx.x;
  int lane = t & 63, wid = t >> 6;
  int fr = lane & 15, fq = lane >> 4;
  int m0 = b*LQ + c*QC;

  __shared__ unsigned short XT[HD*QC];
  __shared__ unsigned short Wt[4*16*32];
  __shared__ float slA[QC], dtlA[QC], elA[QC];

  const float* csb = cs + ((size_t)(b*NH+h)*NC + c)*QC;

  for (int idx = t; idx < (HD/8)*QC; idx += 256) {
    int pg = idx % 10, i = idx / 10;
    uint4 v = make_uint4(0,0,0,0);
    if (i < len)
      v = *(const uint4*)(xcb + (size_t)(m0+i)*CONVD + h*HD + pg*8);
    union { uint4 u; unsigned short us[8]; } cv; cv.u = v;
    #pragma unroll
    for (int e = 0; e < 8; e++)
      XT[swz64(pg*8+e, i)] = cv.us[e];
  }
  if (t < QC) {
    float s = csb[t];
    slA[t] = s;
    elA[t] = __expf(s);
    dtlA[t] = (t < len) ? dtb[((size_t)(m0+t))*NH + h] : 0.f;
  }
  __syncthreads();

  int row16 = wid*16 + fr;
  bf16x8 fa = {};
  if (row16 < len)
    fa = *(const bf16x8*)(xcb + (size_t)(m0+row16)*CONVD + DI + DS + fq*8);

  size_t hb = ((size_t)(b*NC + c)*NH + h)*(HD*DS);
  f32x4 acc[5];
  #pragma unroll
  for (int j = 0; j < 5; j++) {
    int p = j*16 + fr;
    bf16x8 fb = *(const bf16x8*)(H0h + hb + (size_t)p*DS + fq*8);
    f32x4 z = {};
    acc[j] = __builtin_amdgcn_mfma_f32_16x16x32_bf16(fa, fb, z, 0, 0, 0);
  }
  #pragma unroll
  for (int rr = 0; rr < 4; rr++) {
    float el = elA[wid*16 + fq*4 + rr];
    #pragma unroll
    for (int j = 0; j < 5; j++) acc[j][rr] *= el;
  }

  int wbase = wid << 9;
  for (int sc = 0; sc < 2; sc++) {
    int i0 = sc*32;
    #pragma unroll
    for (int jt = 0; jt < 2; jt++) {
      int col = i0 + jt*16 + fr;
      bf16x8 fbv = {};
      if (col < len)
        fbv = *(const bf16x8*)(xcb + (size_t)(m0+col)*CONVD + DI + fq*8);
      float sc_col = slA[col], dt_col = dtlA[col];
      f32x4 z = {};
      f32x4 g = __builtin_amdgcn_mfma_f32_16x16x32_bf16(fa, fbv, z, 0, 0, 0);
      #pragma unroll
      for (int rr = 0; rr < 4; rr++) {
        int lr = fq*4 + rr;
        int row = wid*16 + lr;
        float v = 0.f;
        if (col <= row)
          v = g[rr] * __expf(slA[row] - sc_col) * dt_col;
        int lc = jt*16 + fr;
        int slot = (lc >> 3) ^ (lr & 3);
        Wt[wbase + (lr<<5) + (slot<<3) + (lc&7)] = f2bf(v);
      }
    }
    bf16x8 wa = *(const bf16x8*)&Wt[wbase + (fr<<5) + ((fq ^ (fr&3))<<3)];
    #pragma unroll
    for (int j = 0; j < 5; j++) {
      int p = j*16 + fr;
      bf16x8 xb = *(const bf16x8*)&XT[swz64(p, i0 + fq*8)];
      acc[j] = __builtin_amdgcn_mfma_f32_16x16x32_bf16(wa, xb, acc[j], 0, 0, 0);
    }
  }

  float dpv = Dp[h];
  #pragma unroll
  for (int rr = 0; rr < 4; rr++) {
    int l = wid*16 + fq*4 + rr;
    if (l >= len) continue;
    size_t m = m0 + l;
    float ssp = 0.f;
    #pragma unroll
    for (int j = 0; j < 5; j++) {
      int p = j*16 + fr;
      int cc = h*HD + p;
      float xv = bf2f(XT[swz64(p, l)]);
      float y = acc[j][rr] + xv*dpv;
      float zv = bf2f(zxh[m*DIP + cc]);
      y *= zv / (1.f + __expf(-zv));
      ygb[m*DI + cc] = f2bf(y);
      ssp = fmaf(y, y, ssp);
    }
    #pragma unroll
    for (int o = 1; o < 16; o <<= 1) ssp += __shfl_xor(ssp, o);
    if (fr == 0) ssum8[m*NH + h] = ssp;
  }
}

// ---------------- K7: out^T = (w2*rsw) @ ygb^T, rsv in epilogue ----------------
__global__ __launch_bounds__(256) void k_gemm2_mfma(
    const unsigned short* __restrict__ W2h, const unsigned short* __restrict__ Ygh,
    const float* __restrict__ ssum8, float* __restrict__ out)
{
  __shared__ unsigned short As[2][128*32];
  __shared__ unsigned short Bs[2][128*32];
  int id = blockIdx.x;
  int xcd = id & 7, pos = id >> 3;
  const int q = 48, r = 3;
  int swz = (xcd < r ? xcd*(q+1) : r*(q+1) + (xcd-r)*q) + pos;
  int c0 = (swz % 3) * 128;
  int t0 = (swz / 3) * 128;
  int tid = threadIdx.x;
  int lane = tid & 63, wid = tid >> 6;
  int wr = wid >> 1, wc = wid & 1;
  int fr = lane & 15, fq = lane >> 4;
  int srow = lane >> 2;
  int scol = (lane & 3) * 8;

#define G2_STAGE(buf, kk)                                                   \
  {                                                                         \
    _Pragma("unroll")                                                       \
    for (int i = 0; i < 2; i++) {                                           \
      int seg = wid + i*4;                                                  \
      int rowA = seg*16 + srow;                                             \
      int ga = c0 + rowA; if (ga > CDIM-1) ga = CDIM-1;                     \
      gload16(W2h + (size_t)ga*DI + (kk) + scol, &As[buf][seg*512]);        \
      int gb = t0 + rowA; if (gb > MQ-1) gb = MQ-1;                         \
      gload16(Ygh + (size_t)gb*DI + (kk) + scol, &Bs[buf][seg*512]);        \
    }                                                                       \
  }

#define G2_COMPUTE(buf)                                                     \
  {                                                                         \
    bf16x8 fa[4], fb[4];                                                    \
    _Pragma("unroll")                                                       \
    for (int i = 0; i < 4; i++) {                                           \
      fa[i] = *(const bf16x8*)&As[buf][(wr*64 + i*16 + fr)*32 + fq*8];      \
      fb[i] = *(const bf16x8*)&Bs[buf][(wc*64 + i*16 + fr)*32 + fq*8];      \
    }                                                                       \
    _Pragma("unroll")                                                       \
    for (int i = 0; i < 4; i++)                                             \
      _Pragma("unroll")                                                     \
      for (int j = 0; j < 4; j++)                                           \
        acc[i][j] = __builtin_amdgcn_mfma_f32_16x16x32_bf16(fa[i], fb[j], acc[i][j], 0, 0, 0); \
  }

  f32x4 acc[4][4] = {};
  G2_STAGE(0, 0);
  __syncthreads();
  int cur = 0;
  for (int k0 = 32; k0 < DI; k0 += 32) {
    G2_STAGE(cur^1, k0);
    G2_COMPUTE(cur);
    __syncthreads();
    cur ^= 1;
  }
  G2_COMPUTE(cur);

  float rsvj[4];
  #pragma unroll
  for (int j = 0; j < 4; j++) {
    int tok = t0 + wc*64 + j*16 + fr;
    float ss = 0.f;
    if (tok < MQ) {
      float4 a = *(const float4*)(ssum8 + (size_t)tok*NH);
      float4 bb = *(const float4*)(ssum8 + (size_t)tok*NH + 4);
      ss = (a.x + a.y + a.z + a.w) + (bb.x + bb.y + bb.z + bb.w);
    }
    rsvj[j] = rsqrtf(ss*(1.0f/DI) + 1e-5f);
  }

  #pragma unroll
  for (int i = 0; i < 4; i++) {
    #pragma unroll
    for (int j = 0; j < 4; j++) {
      #pragma unroll
      for (int rr = 0; rr < 4; rr++) {
        int ch  = c0 + wr*64 + i*16 + fq*4 + rr;
        int tok = t0 + wc*64 + j*16 + fr;
        if (ch < CDIM && tok < MQ) {
          int b = tok / LQ, l = tok % LQ;
          if (l < NTQ)
            out[((size_t)(b*CDIM + ch))*NTQ + l] = acc[i][j][rr] * rsvj[j];
        }
      }
    }
  }
}

extern "C" void kernel_launch(void* const* d_in, const int* in_sizes, int n_in,
                              void* d_out, int out_size, void* d_ws, size_t ws_size,
                              hipStream_t stream)
{
  const float* x       = (const float*)d_in[0];
  const float* pc      = (const float*)d_in[1];
  const float* lnw     = (const float*)d_in[2];
  const float* lnb     = (const float*)d_in[3];
  const float* w1      = (const float*)d_in[4];
  const float* cw      = (const float*)d_in[5];
  const float* cb      = (const float*)d_in[6];
  const float* dt_bias = (const float*)d_in[7];
  const float* A_log   = (const float*)d_in[8];
  const float* Dp      = (const float*)d_in[9];
  const float* rsw     = (const float*)d_in[10];
  const float* w2      = (const float*)d_in[11];
  const float* pg      = (const float*)d_in[12];
  const float* pew     = (const float*)d_in[13];
  const float* nap     = (const float*)d_in[14];
  const int*   plab    = (const int*)d_in[15];
  float* out = (float*)d_out;

  unsigned short* xnh  = (unsigned short*)d_ws;                     // MQ*CDIM bf16
  unsigned short* zxh  = xnh + (size_t)MQ*CDIM;                     // MQ*DIP bf16
  float* dtraw = (float*)(zxh + (size_t)MQ*DIP);                    // MQ*NH f32
  unsigned short* xcb  = (unsigned short*)(dtraw + (size_t)MQ*NH);  // MQ*CONVD bf16
  float* dtb = (float*)(xcb + (size_t)MQ*CONVD);                    // MQ*NH f32
  float* cs  = dtb + (size_t)MQ*NH;                                 // B*NH*NC*QC
  float* Dc  = cs  + (size_t)BQ*NH*NC*QC;                           // B*NH*NC
  float* Sb  = Dc  + (size_t)BQ*NH*NC;                              // B*NC*NH*HD*DS f32
  unsigned short* H0h = (unsigned short*)(Sb + (size_t)BQ*NC*NH*HD*DS);
  unsigned short* ygb = H0h + (size_t)BQ*NC*NH*HD*DS;               // MQ*DI bf16
  unsigned short* w1h = ygb + (size_t)MQ*DI;                        // DIP*CDIM bf16
  unsigned short* w2h = w1h + (size_t)DIP*CDIM;                     // CDIM*DI bf16 (rsw folded)
  float* muP = (float*)(w2h + (size_t)CDIM*DI);                     // 8*B*NTQ f32
  float* s2P = muP + (size_t)8*BQ*NTQ;                              // 8*B*NTQ f32
  float* ssum8 = s2P + (size_t)8*BQ*NTQ;                            // MQ*NH f32

  const int NBW = (DIP*CDIM/4 + CDIM*DI/4 + 255)/256;
  k_prep<<<NBW + 512 + 32, 256, 0, stream>>>(
      w1, w1h, w2, rsw, w2h, x, muP, s2P,
      pc, lnw, lnb, pg, pew, nap, plab, xnh);
  dim3 gn(NTQ/64, CDIM/64, BQ);
  k_norm_t<<<gn, 256, 0, stream>>>(x, muP, s2P, lnw, lnb, xnh);
  k_gemm1_mfma<<<129*11, 256, 0, stream>>>(xnh, w1h, zxh, dtraw);
  k_conv<<<((MQ/8)*(CONVD/4) + 255)/256, 256, 0, stream>>>(zxh, cw, cb, xcb);
  dim3 gc(NC, NH, BQ);
  k_cumsum_state<<<gc, 256, 0, stream>>>(dtraw, dt_bias, A_log, xcb, dtb, cs, Dc, Sb);
  k_state_scan<<<(BQ*NH*HD*DS)/256, 256, 0, stream>>>(Sb, Dc, H0h);
  k_chunk_y_mfma<<<gc, 256, 0, stream>>>(xcb, zxh, dtb, cs, H0h, Dp, ygb, ssum8);
  k_gemm2_mfma<<<129*3, 256, 0, stream>>>(w2h, ygb, ssum8, out);
}